// Round 10
// baseline (199.360 us; speedup 1.0000x reference)
//
#include <hip/hip_runtime.h>

typedef unsigned short u16t;
typedef __attribute__((ext_vector_type(8))) short bf16x8;
typedef __attribute__((ext_vector_type(4))) float f32x4;

#define DM   1024
#define SEQL 2048
#define NHD  16
#define HDD  64

#define GLL16(g, l) __builtin_amdgcn_global_load_lds( \
    (const __attribute__((address_space(1))) void*)(g), \
    (__attribute__((address_space(3))) void*)(l), 16, 0, 0)

#if defined(__has_builtin)
#if __has_builtin(__builtin_amdgcn_exp2f)
#define EXP2(x) __builtin_amdgcn_exp2f(x)
#else
#define EXP2(x) exp2f(x)
#endif
#else
#define EXP2(x) exp2f(x)
#endif

__device__ __forceinline__ u16t f2bf(float f) {
  unsigned u = __float_as_uint(f);
  return (u16t)((u + 0x7fffu + ((u >> 16) & 1u)) >> 16);   // RNE
}
// pack two finite floats to (bf16(a) | bf16(b)<<16), round-half-up
__device__ __forceinline__ unsigned pack_bf16_2(float a, float b) {
  const unsigned ua = __float_as_uint(a) + 0x8000u;
  const unsigned ub = __float_as_uint(b) + 0x8000u;
  return __builtin_amdgcn_perm(ub, ua, 0x07060302);
}
// (bf16pair_a + bf16pair_c) * inv, repacked
__device__ __forceinline__ unsigned addpk(unsigned a, unsigned c, float inv) {
  const float lo = __uint_as_float(a << 16) + __uint_as_float(c << 16);
  const float hi = __uint_as_float(a & 0xFFFF0000u) + __uint_as_float(c & 0xFFFF0000u);
  return pack_bf16_2(lo * inv, hi * inv);
}

// ---------------------------------------------------------------------------
// fp32 -> bf16 conversion: x (4M elems) + 4 weights (1M each)
// ---------------------------------------------------------------------------
struct ConvArgs { const float* src[5]; u16t* dst[5]; };

__global__ __launch_bounds__(256) void conv_kernel(ConvArgs a) {
  const int gid = blockIdx.x * 256 + threadIdx.x;
  const int e = gid << 2;
  int sel, off;
  if (e < 4194304) { sel = 0; off = e; }
  else { const int r = e - 4194304; sel = 1 + (r >> 20); off = r & 1048575; }
  const float4 f = *(const float4*)(a.src[sel] + off);
  union { u16t s[4]; uint2 u; } o;
  o.s[0] = f2bf(f.x); o.s[1] = f2bf(f.y); o.s[2] = f2bf(f.z); o.s[3] = f2bf(f.w);
  *(uint2*)(a.dst[sel] + off) = o.u;
}

__device__ __forceinline__ int gslot(int m, int kc) { return (m << 2) + (kc ^ ((m >> 1) & 3)); }

// ---------------------------------------------------------------------------
// QKV GEMM.  X:[4096][1024], W:[1024][1024] rm.  128(token)x128(d) tile, BK=32.
// Double-buffered GLL pipeline; epilogue Es aliases staging (barrier-guarded).
// MODE 1 (Q,K): computes Y^T (operand swap) -> coalesced 16B stores [bh][n][hd]
// MODE 2 (V): normal orientation, token groups permuted by pos(), stored as
//   V^T [bh][hd][n'] so the attention PV A-fragment is one ds_read_b128.
// ---------------------------------------------------------------------------
template<int MODE>
__device__ __forceinline__ void qkv_body(
    const u16t* __restrict__ X, const u16t* __restrict__ W,
    const float* __restrict__ bias, float oscale, u16t* __restrict__ outB,
    u16t* smem)
{
  u16t* const Es = smem;                 // 17408 elems, aliases staging

  const int tid = threadIdx.x;
  const int l = tid & 63, w = tid >> 6, q = l >> 4, ln = l & 15;
  const int trow0 = blockIdx.y << 7;    // token tile base
  const int dcol0 = blockIdx.x << 7;    // d tile base
  const int wm = (w >> 1) << 6, wn = (w & 1) << 6;

  const int s0 = (w << 6) + l, s1 = s0 + 256;
  const int m0 = s0 >> 2, kc0 = (s0 & 3) ^ ((m0 >> 1) & 3);
  const int m1 = s1 >> 2, kc1 = (s1 & 3) ^ ((m1 >> 1) & 3);
  const u16t* gA0 = X + (size_t)(trow0 + m0) * DM + (kc0 << 3);
  const u16t* gA1 = X + (size_t)(trow0 + m1) * DM + (kc1 << 3);
  const u16t* gB0 = W + (size_t)(dcol0 + m0) * DM + (kc0 << 3);
  const u16t* gB1 = W + (size_t)(dcol0 + m1) * DM + (kc1 << 3);
  const int dO0 = (w << 6) << 3;               // LDS elem offsets
  const int dO1 = ((w << 6) + 256) << 3;

  f32x4 acc[4][4] = {};

  GLL16(gA0, smem + dO0);
  GLL16(gA1, smem + dO1);
  GLL16(gB0, smem + 4096 + dO0);
  GLL16(gB1, smem + 4096 + dO1);

  for (int kt = 0; kt < DM; kt += 32) {
    const int it = kt >> 5;
    u16t* const curA = smem + ((it & 1) ? 8192 : 0);
    u16t* const curB = curA + 4096;
    __syncthreads();                   // tile `it` loads complete; prev reads done
    if (kt + 32 < DM) {                // prefetch tile it+1 into alt buffer
      u16t* const nA = smem + ((it & 1) ? 0 : 8192);
      u16t* const nB = nA + 4096;
      GLL16(gA0 + kt + 32, nA + dO0);
      GLL16(gA1 + kt + 32, nA + dO1);
      GLL16(gB0 + kt + 32, nB + dO0);
      GLL16(gB1 + kt + 32, nB + dO1);
    }

    bf16x8 af[4], bfr[4];
    #pragma unroll
    for (int mi = 0; mi < 4; ++mi) {
      const int r = wm + (mi << 4) + ln;
      af[mi] = *(const bf16x8*)&((MODE == 1 ? curB : curA)[gslot(r, q) << 3]);
    }
    #pragma unroll
    for (int ni = 0; ni < 4; ++ni) {
      const int r = wn + (ni << 4) + ln;
      bfr[ni] = *(const bf16x8*)&((MODE == 1 ? curA : curB)[gslot(r, q) << 3]);
    }
    #pragma unroll
    for (int mi = 0; mi < 4; ++mi)
      #pragma unroll
      for (int ni = 0; ni < 4; ++ni)
        acc[mi][ni] = __builtin_amdgcn_mfma_f32_16x16x32_bf16(af[mi], bfr[ni], acc[mi][ni], 0, 0, 0);
  }

  __syncthreads();   // staging dead; Es (aliased) now safe to write

  if (MODE == 1) {
    #pragma unroll
    for (int mi = 0; mi < 4; ++mi) {
      const int dl = wm + (mi << 4) + (q << 2);
      const float4 b4 = *(const float4*)&bias[dcol0 + dl];
      #pragma unroll
      for (int ni = 0; ni < 4; ++ni) {
        const int tl = wn + (ni << 4) + ln;
        uint2 pk;
        pk.x = pack_bf16_2((acc[mi][ni][0] + b4.x) * oscale, (acc[mi][ni][1] + b4.y) * oscale);
        pk.y = pack_bf16_2((acc[mi][ni][2] + b4.z) * oscale, (acc[mi][ni][3] + b4.w) * oscale);
        *(uint2*)&Es[tl * 136 + dl] = pk;
      }
    }
    __syncthreads();
    #pragma unroll
    for (int it = 0; it < 8; ++it) {
      const int u = (it << 8) + tid;
      const int tl = u >> 4, c8 = u & 15;
      const uint4 vv = *(const uint4*)&Es[tl * 136 + (c8 << 3)];
      const int tok = trow0 + tl;
      const int b = tok >> 11, n = tok & (SEQL - 1);
      const int dg = dcol0 + (c8 << 3);
      const int h = dg >> 6, hd = dg & 63;
      *(uint4*)&outB[((size_t)(b * NHD + h) * SEQL + n) * HDD + hd] = vv;
    }
  } else {
    #pragma unroll
    for (int ni = 0; ni < 4; ++ni) {
      const int dl = wn + (ni << 4) + ln;
      const float bv = bias[dcol0 + dl];
      #pragma unroll
      for (int mi = 0; mi < 4; ++mi) {
        const int g = (wm >> 2) + (mi << 2) + q;   // token group (of 4), 0..31
        const int g6 = g & 15;
        const int gp = (g & 16) | (g6 & 8) | ((g6 & 3) << 1) | ((g6 >> 2) & 1);
        uint2 pk;
        pk.x = pack_bf16_2(acc[mi][ni][0] + bv, acc[mi][ni][1] + bv);
        pk.y = pack_bf16_2(acc[mi][ni][2] + bv, acc[mi][ni][3] + bv);
        *(uint2*)&Es[dl * 136 + (gp << 2)] = pk;
      }
    }
    __syncthreads();
    #pragma unroll
    for (int it = 0; it < 8; ++it) {
      const int u = (it << 8) + tid;
      const int dl = u >> 4, c8 = u & 15;
      const uint4 vv = *(const uint4*)&Es[dl * 136 + (c8 << 3)];
      const int dg = dcol0 + dl;
      const int h = dg >> 6, hd = dg & 63;
      const int b = trow0 >> 11;
      const int n = (trow0 & (SEQL - 1)) + (c8 << 3);
      *(uint4*)&outB[((size_t)(b * NHD + h) * HDD + hd) * SEQL + n] = vv;
    }
  }
}

struct QKVArgs { const u16t* W[3]; const float* b[3]; u16t* dst[3]; };

__global__ __launch_bounds__(256) void qkv_kernel(const u16t* __restrict__ X, QKVArgs g) {
  __shared__ alignas(16) u16t smem[17408];
  const int z = blockIdx.z;
  if (z == 2)      qkv_body<2>(X, g.W[2], g.b[2], 1.0f, g.dst[2], smem);
  else if (z == 1) qkv_body<1>(X, g.W[1], g.b[1], 1.0f, g.dst[1], smem);
  else             qkv_body<1>(X, g.W[0], g.b[0], 0.04508422f, g.dst[0], smem);
  // Q pre-scaled by log2(e)/32 so attention uses exp2 directly
}

// ---------------------------------------------------------------------------
// MFMA flash attention, KEY-SPLIT 2x. Block = (q-tile 128, bh, z in {0,1}).
// Writes UNNORMALIZED partial O (bf16, ctx layout) + partial sums l.
// Q direct global->regs; LDS = K/V dbuf (32 KB) -> 4 blocks/CU. Row sums via
// ones-MFMA. P = exp2(S') since Q carries log2e/32.
// ---------------------------------------------------------------------------
__global__ __launch_bounds__(256, 4) void attn_kernel(
    const u16t* __restrict__ Qb, const u16t* __restrict__ Kb,
    const u16t* __restrict__ Vt, u16t* __restrict__ p0,
    u16t* __restrict__ p1, float* __restrict__ ls)
{
  __shared__ alignas(16) u16t smem[16384];   // 32 KB: K/V dbuf; Os aliases

  const int tid = threadIdx.x;              // 0..255
  const int l = tid & 63, w = tid >> 6;     // wave 0..3
  const int q = l >> 4, ln = l & 15;
  const int bh = blockIdx.y, q0 = blockIdx.x << 7, z = blockIdx.z;
  const int kbase = z << 10;
  const size_t hb = (size_t)bh * SEQL * HDD;
  const u16t* Qg = Qb + hb;
  const u16t* Kg = Kb + hb;
  const u16t* Vg = Vt + hb;   // [hd][n-permuted]

  bf16x8 qf[2][2];
  #pragma unroll
  for (int g = 0; g < 2; ++g) {
    const int qr = q0 + (w << 5) + (g << 4) + ln;
    #pragma unroll
    for (int ks = 0; ks < 2; ++ks)
      qf[g][ks] = *(const bf16x8*)(Qg + (size_t)qr * HDD + (((ks << 2) + q) << 3));
  }

  const int u0 = tid,       r0 = u0 >> 3, c0 = (u0 & 7) ^ (r0 & 7);
  const int u1 = 256 + tid, r1 = u1 >> 3, c1 = (u1 & 7) ^ (r1 & 7);
  const u16t* const kS0 = Kg + (size_t)(kbase + r0) * HDD + (c0 << 3);
  const u16t* const kS1 = Kg + (size_t)(kbase + r1) * HDD + (c1 << 3);
  const u16t* const vS0 = Vg + (size_t)r0 * SEQL + kbase + (c0 << 3);
  const u16t* const vS1 = Vg + (size_t)r1 * SEQL + kbase + (c1 << 3);
  const int dK0 = (w << 6) << 3, dK1 = (256 + (w << 6)) << 3;

  GLL16(kS0, smem + dK0);
  GLL16(kS1, smem + dK1);
  GLL16(vS0, smem + 4096 + dK0);
  GLL16(vS1, smem + 4096 + dK1);

  const short one_s = (short)0x3F80;
  const bf16x8 ones = { one_s, one_s, one_s, one_s, one_s, one_s, one_s, one_s };

  f32x4 accO[2][4] = {};
  f32x4 accL[2] = {};

  for (int t = 0; t < 16; ++t) {
    const int cb = (t & 1) ? 8192 : 0;
    u16t* const Ks = smem + cb;
    u16t* const Vs = smem + cb + 4096;
    __syncthreads();               // tile t loads complete; prev reads done
    if (t + 1 < 16) {
      const int nb = (t & 1) ? 0 : 8192;
      const int ko = (t + 1) << 6;
      GLL16(kS0 + (size_t)ko * HDD, smem + nb + dK0);
      GLL16(kS1 + (size_t)ko * HDD, smem + nb + dK1);
      GLL16(vS0 + ko, smem + nb + 4096 + dK0);
      GLL16(vS1 + ko, smem + nb + 4096 + dK1);
    }

    f32x4 sc[2][4] = {{}, {}};
    #pragma unroll
    for (int ks = 0; ks < 2; ++ks) {
      const int hc = (ks << 2) + q;
      #pragma unroll
      for (int ni = 0; ni < 4; ++ni) {
        const int kr = (ni << 4) + ln;
        const bf16x8 ak = *(const bf16x8*)&Ks[((kr << 3) + (hc ^ (kr & 7))) << 3];
        #pragma unroll
        for (int g = 0; g < 2; ++g)
          sc[g][ni] = __builtin_amdgcn_mfma_f32_16x16x32_bf16(ak, qf[g][ks], sc[g][ni], 0, 0, 0);
      }
    }

    unsigned pk01[2][4], pk23[2][4];
    #pragma unroll
    for (int g = 0; g < 2; ++g)
      #pragma unroll
      for (int ni = 0; ni < 4; ++ni) {
        const float e0 = EXP2(sc[g][ni][0]);
        const float e1 = EXP2(sc[g][ni][1]);
        const float e2 = EXP2(sc[g][ni][2]);
        const float e3 = EXP2(sc[g][ni][3]);
        pk01[g][ni] = pack_bf16_2(e0, e1);
        pk23[g][ni] = pack_bf16_2(e2, e3);
      }

    #pragma unroll
    for (int ks = 0; ks < 2; ++ks) {
      union { unsigned u[4]; bf16x8 v; } bfv[2];
      #pragma unroll
      for (int g = 0; g < 2; ++g) {
        bfv[g].u[0] = pk01[g][(ks << 1) + 0];
        bfv[g].u[1] = pk23[g][(ks << 1) + 0];
        bfv[g].u[2] = pk01[g][(ks << 1) + 1];
        bfv[g].u[3] = pk23[g][(ks << 1) + 1];
      }
      #pragma unroll
      for (int g = 0; g < 2; ++g)
        accL[g] = __builtin_amdgcn_mfma_f32_16x16x32_bf16(ones, bfv[g].v, accL[g], 0, 0, 0);
      const int c = (ks << 2) + q;
      #pragma unroll
      for (int nio = 0; nio < 4; ++nio) {
        const int vr = (nio << 4) + ln;
        const bf16x8 av = *(const bf16x8*)&Vs[((vr << 3) + (c ^ (vr & 7))) << 3];
        #pragma unroll
        for (int g = 0; g < 2; ++g)
          accO[g][nio] = __builtin_amdgcn_mfma_f32_16x16x32_bf16(av, bfv[g].v, accO[g][nio], 0, 0, 0);
      }
    }
  }

  if (q == 0) {
    #pragma unroll
    for (int g = 0; g < 2; ++g) {
      const int token = q0 + (w << 5) + (g << 4) + ln;
      ls[(z << 16) + (bh << 11) + token] = accL[g][0];
    }
  }

  __syncthreads();   // last tile's DS reads done before Os overwrite
  #pragma unroll
  for (int g = 0; g < 2; ++g) {
    const int tl = (w << 5) + (g << 4) + ln;
    #pragma unroll
    for (int nio = 0; nio < 4; ++nio) {
      uint2 pk;
      pk.x = pack_bf16_2(accO[g][nio][0], accO[g][nio][1]);
      pk.y = pack_bf16_2(accO[g][nio][2], accO[g][nio][3]);
      *(uint2*)&smem[tl * 72 + (nio << 4) + (q << 2)] = pk;
    }
  }
  __syncthreads();
  u16t* const pbuf = z ? p1 : p0;
  const int h = bh & (NHD - 1), bi = bh >> 4;
  #pragma unroll
  for (int it = 0; it < 4; ++it) {
    const int u = (it << 8) + tid;
    const int tl = u >> 3, c8 = u & 7;
    const uint4 vv = *(const uint4*)&smem[tl * 72 + (c8 << 3)];
    *(uint4*)&pbuf[((size_t)(bi * SEQL + q0 + tl)) * DM + (h << 6) + (c8 << 3)] = vv;
  }
}

// ---------------------------------------------------------------------------
// FUSED output projection: out = ((P0+P1)/l) @ Wo^T + bo.
// Tile 128(token) x 64(d-out), grid (16,32)=512 blocks (2/CU, 8 waves/CU).
// A-operand staged via VALU (load p0+p1, add, x inv[token][head] from an
// 8 KB LDS table, pack bf16, ds_write); B (Wo) staged via GLL. Both
// double-buffered: prefetch for t+1 issued at top of iter t.
// Replaces the separate reduce kernel (same rounding point: bf16 of
// normalized O). Valid because each BK=32 slab lies within one head.
// ---------------------------------------------------------------------------
__global__ __launch_bounds__(256) void outproj_kernel(
    const u16t* __restrict__ p0, const u16t* __restrict__ p1,
    const float* __restrict__ ls, const u16t* __restrict__ W,
    const float* __restrict__ bias, float* __restrict__ outF)
{
  __shared__ alignas(16) u16t smem[16384];     // A0@0 B0@4096 A1@6144 B1@10240 | invS@12288
  float* const invS = (float*)(smem + 12288);  // [128 tokens][16 heads]

  const int tid = threadIdx.x;
  const int l = tid & 63, w = tid >> 6, q = l >> 4, ln = l & 15;
  const int row0 = blockIdx.y << 7;   // token base
  const int col0 = blockIdx.x << 6;   // d-out base
  const int wm = (w >> 1) << 6, wn = (w & 1) << 5;

  // invS table: 2048 entries, 8 per thread
  #pragma unroll
  for (int i = 0; i < 8; ++i) {
    const int idx = (tid << 3) + i;          // token_local*16 + h
    const int tok = row0 + (idx >> 4), h = idx & 15;
    const int li = ((((tok >> 11) << 4) + h) << 11) + (tok & (SEQL - 1));
    invS[idx] = 1.0f / (ls[li] + ls[65536 + li]);
  }

  // A staging geometry (VALU path): units s0=tid, s1=tid+256 of 512
  const int m0 = tid >> 2,         kc0 = (tid & 3) ^ ((m0 >> 1) & 3);
  const int m1 = (tid + 256) >> 2, kc1 = ((tid + 256) & 3) ^ ((m1 >> 1) & 3);
  const u16t* const a00 = p0 + (size_t)(row0 + m0) * DM + (kc0 << 3);
  const u16t* const a01 = p1 + (size_t)(row0 + m0) * DM + (kc0 << 3);
  const u16t* const a10 = p0 + (size_t)(row0 + m1) * DM + (kc1 << 3);
  const u16t* const a11 = p1 + (size_t)(row0 + m1) * DM + (kc1 << 3);
  // B staging (GLL): unit tid of 256
  const int mB = tid >> 2, kcB = (tid & 3) ^ ((mB >> 1) & 3);
  const u16t* const gB = W + (size_t)(col0 + mB) * DM + (kcB << 3);
  const int dBo = (w << 6) << 3;

  uint4 r00 = *(const uint4*)a00, r01 = *(const uint4*)a01;
  uint4 r10 = *(const uint4*)a10, r11 = *(const uint4*)a11;
  GLL16(gB, smem + 4096 + dBo);
  __syncthreads();                 // invS visible; B(0) complete
  {                                // stage A(0) into buf0 (h = 0)
    const float inv0 = invS[m0 << 4];
    const float inv1 = invS[m1 << 4];
    uint4 o0, o1;
    o0.x = addpk(r00.x, r01.x, inv0); o0.y = addpk(r00.y, r01.y, inv0);
    o0.z = addpk(r00.z, r01.z, inv0); o0.w = addpk(r00.w, r01.w, inv0);
    o1.x = addpk(r10.x, r11.x, inv1); o1.y = addpk(r10.y, r11.y, inv1);
    o1.z = addpk(r10.z, r11.z, inv1); o1.w = addpk(r10.w, r11.w, inv1);
    *(uint4*)&smem[tid << 3] = o0;
    *(uint4*)&smem[(tid + 256) << 3] = o1;
  }
  r00 = *(const uint4*)(a00 + 32); r01 = *(const uint4*)(a01 + 32);
  r10 = *(const uint4*)(a10 + 32); r11 = *(const uint4*)(a11 + 32);
  __syncthreads();                 // A(0) writes visible

  f32x4 acc[4][2] = {};

  for (int t = 0; t < 32; ++t) {
    u16t* const cur = smem + ((t & 1) ? 6144 : 0);
    if (t + 1 < 32) {
      u16t* const nxt = smem + ((t & 1) ? 0 : 6144);
      GLL16(gB + ((t + 1) << 5), nxt + 4096 + dBo);
      const int h1 = (t + 1) >> 1;
      const float inv0 = invS[(m0 << 4) + h1];
      const float inv1 = invS[(m1 << 4) + h1];
      uint4 o0, o1;
      o0.x = addpk(r00.x, r01.x, inv0); o0.y = addpk(r00.y, r01.y, inv0);
      o0.z = addpk(r00.z, r01.z, inv0); o0.w = addpk(r00.w, r01.w, inv0);
      o1.x = addpk(r10.x, r11.x, inv1); o1.y = addpk(r10.y, r11.y, inv1);
      o1.z = addpk(r10.z, r11.z, inv1); o1.w = addpk(r10.w, r11.w, inv1);
      *(uint4*)&nxt[tid << 3] = o0;
      *(uint4*)&nxt[(tid + 256) << 3] = o1;
      if (t + 2 < 32) {
        const int kt2 = (t + 2) << 5;
        r00 = *(const uint4*)(a00 + kt2); r01 = *(const uint4*)(a01 + kt2);
        r10 = *(const uint4*)(a10 + kt2); r11 = *(const uint4*)(a11 + kt2);
      }
    }

    bf16x8 af[4], bfr[2];
    #pragma unroll
    for (int mi = 0; mi < 4; ++mi)
      af[mi] = *(const bf16x8*)&cur[gslot(wm + (mi << 4) + ln, q) << 3];
    #pragma unroll
    for (int ni = 0; ni < 2; ++ni)
      bfr[ni] = *(const bf16x8*)&cur[4096 + (gslot(wn + (ni << 4) + ln, q) << 3)];
    #pragma unroll
    for (int mi = 0; mi < 4; ++mi)
      #pragma unroll
      for (int ni = 0; ni < 2; ++ni)
        acc[mi][ni] = __builtin_amdgcn_mfma_f32_16x16x32_bf16(af[mi], bfr[ni], acc[mi][ni], 0, 0, 0);
    __syncthreads();               // publish t+1 bufs; t's readers done
  }

  #pragma unroll
  for (int ni = 0; ni < 2; ++ni) {
    const int col = col0 + wn + (ni << 4) + ln;
    const float bv = bias[col];
    #pragma unroll
    for (int mi = 0; mi < 4; ++mi)
      #pragma unroll
      for (int r = 0; r < 4; ++r) {
        const int row = row0 + wm + (mi << 4) + (q << 2) + r;
        outF[(size_t)row * DM + col] = acc[mi][ni][r] + bv;
      }
  }
}

// ---------------------------------------------------------------------------
extern "C" void kernel_launch(void* const* d_in, const int* in_sizes, int n_in,
                              void* d_out, int out_size, void* d_ws, size_t ws_size,
                              hipStream_t stream)
{
  const float* x  = (const float*)d_in[0];
  const float* Wq = (const float*)d_in[1];
  const float* bq = (const float*)d_in[2];
  const float* Wk = (const float*)d_in[3];
  const float* bk = (const float*)d_in[4];
  const float* Wv = (const float*)d_in[5];
  const float* bv = (const float*)d_in[6];
  const float* Wo = (const float*)d_in[7];
  const float* bo = (const float*)d_in[8];
  float* out = (float*)d_out;

  u16t* p = (u16t*)d_ws;
  u16t* xb  = p;  p += 4194304;   // x bf16; reused as partial O (split 1) after qkv
  u16t* Wqb = p;  p += 1048576;   // reused as lsum (float[2][32][2048]) after qkv
  u16t* Wkb = p;  p += 1048576;
  u16t* Wvb = p;  p += 1048576;
  u16t* Wob = p;  p += 1048576;
  u16t* Qbf = p;  p += 4194304;
  u16t* Kbf = p;  p += 4194304;
  u16t* Vtb = p;  p += 4194304;
  u16t* ctx = p;  p += 4194304;   // partial O (split 0)

  ConvArgs ca;
  ca.src[0] = x;  ca.dst[0] = xb;
  ca.src[1] = Wq; ca.dst[1] = Wqb;
  ca.src[2] = Wk; ca.dst[2] = Wkb;
  ca.src[3] = Wv; ca.dst[3] = Wvb;
  ca.src[4] = Wo; ca.dst[4] = Wob;
  conv_kernel<<<8192, 256, 0, stream>>>(ca);

  QKVArgs qa;
  qa.W[0] = Wqb; qa.W[1] = Wkb; qa.W[2] = Wvb;
  qa.b[0] = bq;  qa.b[1] = bk;  qa.b[2] = bv;
  qa.dst[0] = Qbf; qa.dst[1] = Kbf; qa.dst[2] = Vtb;
  qkv_kernel<<<dim3(8, 32, 3), 256, 0, stream>>>(xb, qa);

  float* lsum = (float*)Wqb;   // Wqb dead after qkv
  attn_kernel<<<dim3(16, 32, 2), 256, 0, stream>>>(Qbf, Kbf, Vtb, ctx, xb, lsum);

  outproj_kernel<<<dim3(16, 32), 256, 0, stream>>>(ctx, xb, lsum, Wob, bo, out);
}

// Round 11
// 183.950 us; speedup vs baseline: 1.0838x; 1.0838x over previous
//
#include <hip/hip_runtime.h>

typedef unsigned short u16t;
typedef __attribute__((ext_vector_type(8))) short bf16x8;
typedef __attribute__((ext_vector_type(4))) float f32x4;

#define DM   1024
#define SEQL 2048
#define NHD  16
#define HDD  64

#define GLL16(g, l) __builtin_amdgcn_global_load_lds( \
    (const __attribute__((address_space(1))) void*)(g), \
    (__attribute__((address_space(3))) void*)(l), 16, 0, 0)

#if defined(__has_builtin)
#if __has_builtin(__builtin_amdgcn_exp2f)
#define EXP2(x) __builtin_amdgcn_exp2f(x)
#else
#define EXP2(x) exp2f(x)
#endif
#else
#define EXP2(x) exp2f(x)
#endif

__device__ __forceinline__ u16t f2bf(float f) {
  unsigned u = __float_as_uint(f);
  return (u16t)((u + 0x7fffu + ((u >> 16) & 1u)) >> 16);   // RNE
}
// pack two finite floats to (bf16(a) | bf16(b)<<16), round-half-up
__device__ __forceinline__ unsigned pack_bf16_2(float a, float b) {
  const unsigned ua = __float_as_uint(a) + 0x8000u;
  const unsigned ub = __float_as_uint(b) + 0x8000u;
  return __builtin_amdgcn_perm(ub, ua, 0x07060302);
}

// ---------------------------------------------------------------------------
// fp32 -> bf16 conversion: x (4M elems) + 4 weights (1M each)
// ---------------------------------------------------------------------------
struct ConvArgs { const float* src[5]; u16t* dst[5]; };

__global__ __launch_bounds__(256) void conv_kernel(ConvArgs a) {
  const int gid = blockIdx.x * 256 + threadIdx.x;
  const int e = gid << 2;
  int sel, off;
  if (e < 4194304) { sel = 0; off = e; }
  else { const int r = e - 4194304; sel = 1 + (r >> 20); off = r & 1048575; }
  const float4 f = *(const float4*)(a.src[sel] + off);
  union { u16t s[4]; uint2 u; } o;
  o.s[0] = f2bf(f.x); o.s[1] = f2bf(f.y); o.s[2] = f2bf(f.z); o.s[3] = f2bf(f.w);
  *(uint2*)(a.dst[sel] + off) = o.u;
}

__device__ __forceinline__ int gslot(int m, int kc) { return (m << 2) + (kc ^ ((m >> 1) & 3)); }

// ---------------------------------------------------------------------------
// QKV GEMM.  X:[4096][1024], W:[1024][1024] rm.  128(token)x128(d) tile, BK=32.
// Double-buffered GLL pipeline; epilogue Es aliases staging (barrier-guarded).
// MODE 1 (Q,K): computes Y^T (operand swap) -> coalesced 16B stores [bh][n][hd]
// MODE 2 (V): normal orientation, token groups permuted by pos(), stored as
//   V^T [bh][hd][n'] so the attention PV A-fragment is one ds_read_b128.
// ---------------------------------------------------------------------------
template<int MODE>
__device__ __forceinline__ void qkv_body(
    const u16t* __restrict__ X, const u16t* __restrict__ W,
    const float* __restrict__ bias, float oscale, u16t* __restrict__ outB,
    u16t* smem)
{
  u16t* const Es = smem;                 // 17408 elems, aliases staging

  const int tid = threadIdx.x;
  const int l = tid & 63, w = tid >> 6, q = l >> 4, ln = l & 15;
  const int trow0 = blockIdx.y << 7;    // token tile base
  const int dcol0 = blockIdx.x << 7;    // d tile base
  const int wm = (w >> 1) << 6, wn = (w & 1) << 6;

  const int s0 = (w << 6) + l, s1 = s0 + 256;
  const int m0 = s0 >> 2, kc0 = (s0 & 3) ^ ((m0 >> 1) & 3);
  const int m1 = s1 >> 2, kc1 = (s1 & 3) ^ ((m1 >> 1) & 3);
  const u16t* gA0 = X + (size_t)(trow0 + m0) * DM + (kc0 << 3);
  const u16t* gA1 = X + (size_t)(trow0 + m1) * DM + (kc1 << 3);
  const u16t* gB0 = W + (size_t)(dcol0 + m0) * DM + (kc0 << 3);
  const u16t* gB1 = W + (size_t)(dcol0 + m1) * DM + (kc1 << 3);
  const int dO0 = (w << 6) << 3;               // LDS elem offsets
  const int dO1 = ((w << 6) + 256) << 3;

  f32x4 acc[4][4] = {};

  GLL16(gA0, smem + dO0);
  GLL16(gA1, smem + dO1);
  GLL16(gB0, smem + 4096 + dO0);
  GLL16(gB1, smem + 4096 + dO1);

  for (int kt = 0; kt < DM; kt += 32) {
    const int it = kt >> 5;
    u16t* const curA = smem + ((it & 1) ? 8192 : 0);
    u16t* const curB = curA + 4096;
    __syncthreads();                   // tile `it` loads complete; prev reads done
    if (kt + 32 < DM) {                // prefetch tile it+1 into alt buffer
      u16t* const nA = smem + ((it & 1) ? 0 : 8192);
      u16t* const nB = nA + 4096;
      GLL16(gA0 + kt + 32, nA + dO0);
      GLL16(gA1 + kt + 32, nA + dO1);
      GLL16(gB0 + kt + 32, nB + dO0);
      GLL16(gB1 + kt + 32, nB + dO1);
    }

    bf16x8 af[4], bfr[4];
    #pragma unroll
    for (int mi = 0; mi < 4; ++mi) {
      const int r = wm + (mi << 4) + ln;
      af[mi] = *(const bf16x8*)&((MODE == 1 ? curB : curA)[gslot(r, q) << 3]);
    }
    #pragma unroll
    for (int ni = 0; ni < 4; ++ni) {
      const int r = wn + (ni << 4) + ln;
      bfr[ni] = *(const bf16x8*)&((MODE == 1 ? curA : curB)[gslot(r, q) << 3]);
    }
    #pragma unroll
    for (int mi = 0; mi < 4; ++mi)
      #pragma unroll
      for (int ni = 0; ni < 4; ++ni)
        acc[mi][ni] = __builtin_amdgcn_mfma_f32_16x16x32_bf16(af[mi], bfr[ni], acc[mi][ni], 0, 0, 0);
  }

  __syncthreads();   // staging dead; Es (aliased) now safe to write

  if (MODE == 1) {
    #pragma unroll
    for (int mi = 0; mi < 4; ++mi) {
      const int dl = wm + (mi << 4) + (q << 2);
      const float4 b4 = *(const float4*)&bias[dcol0 + dl];
      #pragma unroll
      for (int ni = 0; ni < 4; ++ni) {
        const int tl = wn + (ni << 4) + ln;
        uint2 pk;
        pk.x = pack_bf16_2((acc[mi][ni][0] + b4.x) * oscale, (acc[mi][ni][1] + b4.y) * oscale);
        pk.y = pack_bf16_2((acc[mi][ni][2] + b4.z) * oscale, (acc[mi][ni][3] + b4.w) * oscale);
        *(uint2*)&Es[tl * 136 + dl] = pk;
      }
    }
    __syncthreads();
    #pragma unroll
    for (int it = 0; it < 8; ++it) {
      const int u = (it << 8) + tid;
      const int tl = u >> 4, c8 = u & 15;
      const uint4 vv = *(const uint4*)&Es[tl * 136 + (c8 << 3)];
      const int tok = trow0 + tl;
      const int b = tok >> 11, n = tok & (SEQL - 1);
      const int dg = dcol0 + (c8 << 3);
      const int h = dg >> 6, hd = dg & 63;
      *(uint4*)&outB[((size_t)(b * NHD + h) * SEQL + n) * HDD + hd] = vv;
    }
  } else {
    #pragma unroll
    for (int ni = 0; ni < 4; ++ni) {
      const int dl = wn + (ni << 4) + ln;
      const float bv = bias[dcol0 + dl];
      #pragma unroll
      for (int mi = 0; mi < 4; ++mi) {
        const int g = (wm >> 2) + (mi << 2) + q;   // token group (of 4), 0..31
        const int g6 = g & 15;
        const int gp = (g & 16) | (g6 & 8) | ((g6 & 3) << 1) | ((g6 >> 2) & 1);
        uint2 pk;
        pk.x = pack_bf16_2(acc[mi][ni][0] + bv, acc[mi][ni][1] + bv);
        pk.y = pack_bf16_2(acc[mi][ni][2] + bv, acc[mi][ni][3] + bv);
        *(uint2*)&Es[dl * 136 + (gp << 2)] = pk;
      }
    }
    __syncthreads();
    #pragma unroll
    for (int it = 0; it < 8; ++it) {
      const int u = (it << 8) + tid;
      const int dl = u >> 4, c8 = u & 15;
      const uint4 vv = *(const uint4*)&Es[dl * 136 + (c8 << 3)];
      const int dg = dcol0 + dl;
      const int h = dg >> 6, hd = dg & 63;
      const int b = trow0 >> 11;
      const int n = (trow0 & (SEQL - 1)) + (c8 << 3);
      *(uint4*)&outB[((size_t)(b * NHD + h) * HDD + hd) * SEQL + n] = vv;
    }
  }
}

struct QKVArgs { const u16t* W[3]; const float* b[3]; u16t* dst[3]; };

__global__ __launch_bounds__(256) void qkv_kernel(const u16t* __restrict__ X, QKVArgs g) {
  __shared__ alignas(16) u16t smem[17408];
  const int z = blockIdx.z;
  if (z == 2)      qkv_body<2>(X, g.W[2], g.b[2], 1.0f, g.dst[2], smem);
  else if (z == 1) qkv_body<1>(X, g.W[1], g.b[1], 1.0f, g.dst[1], smem);
  else             qkv_body<1>(X, g.W[0], g.b[0], 0.04508422f, g.dst[0], smem);
  // Q pre-scaled by log2(e)/32 so attention uses exp2 directly
}

// ---------------------------------------------------------------------------
// MFMA flash attention, KEY-SPLIT 2x. Block = (q-tile 128, bh, z in {0,1}).
// Writes UNNORMALIZED partial O (bf16, ctx layout) + partial sums l.
// Q direct global->regs; LDS = K/V dbuf (32 KB) -> 4 blocks/CU. Row sums via
// ones-MFMA. P = exp2(S') since Q carries log2e/32.
// ---------------------------------------------------------------------------
__global__ __launch_bounds__(256, 4) void attn_kernel(
    const u16t* __restrict__ Qb, const u16t* __restrict__ Kb,
    const u16t* __restrict__ Vt, u16t* __restrict__ p0,
    u16t* __restrict__ p1, float* __restrict__ ls)
{
  __shared__ alignas(16) u16t smem[16384];   // 32 KB: K/V dbuf; Os aliases

  const int tid = threadIdx.x;              // 0..255
  const int l = tid & 63, w = tid >> 6;     // wave 0..3
  const int q = l >> 4, ln = l & 15;
  const int bh = blockIdx.y, q0 = blockIdx.x << 7, z = blockIdx.z;
  const int kbase = z << 10;
  const size_t hb = (size_t)bh * SEQL * HDD;
  const u16t* Qg = Qb + hb;
  const u16t* Kg = Kb + hb;
  const u16t* Vg = Vt + hb;   // [hd][n-permuted]

  bf16x8 qf[2][2];
  #pragma unroll
  for (int g = 0; g < 2; ++g) {
    const int qr = q0 + (w << 5) + (g << 4) + ln;
    #pragma unroll
    for (int ks = 0; ks < 2; ++ks)
      qf[g][ks] = *(const bf16x8*)(Qg + (size_t)qr * HDD + (((ks << 2) + q) << 3));
  }

  const int u0 = tid,       r0 = u0 >> 3, c0 = (u0 & 7) ^ (r0 & 7);
  const int u1 = 256 + tid, r1 = u1 >> 3, c1 = (u1 & 7) ^ (r1 & 7);
  const u16t* const kS0 = Kg + (size_t)(kbase + r0) * HDD + (c0 << 3);
  const u16t* const kS1 = Kg + (size_t)(kbase + r1) * HDD + (c1 << 3);
  const u16t* const vS0 = Vg + (size_t)r0 * SEQL + kbase + (c0 << 3);
  const u16t* const vS1 = Vg + (size_t)r1 * SEQL + kbase + (c1 << 3);
  const int dK0 = (w << 6) << 3, dK1 = (256 + (w << 6)) << 3;

  GLL16(kS0, smem + dK0);
  GLL16(kS1, smem + dK1);
  GLL16(vS0, smem + 4096 + dK0);
  GLL16(vS1, smem + 4096 + dK1);

  const short one_s = (short)0x3F80;
  const bf16x8 ones = { one_s, one_s, one_s, one_s, one_s, one_s, one_s, one_s };

  f32x4 accO[2][4] = {};
  f32x4 accL[2] = {};

  for (int t = 0; t < 16; ++t) {
    const int cb = (t & 1) ? 8192 : 0;
    u16t* const Ks = smem + cb;
    u16t* const Vs = smem + cb + 4096;
    __syncthreads();               // tile t loads complete; prev reads done
    if (t + 1 < 16) {
      const int nb = (t & 1) ? 0 : 8192;
      const int ko = (t + 1) << 6;
      GLL16(kS0 + (size_t)ko * HDD, smem + nb + dK0);
      GLL16(kS1 + (size_t)ko * HDD, smem + nb + dK1);
      GLL16(vS0 + ko, smem + nb + 4096 + dK0);
      GLL16(vS1 + ko, smem + nb + 4096 + dK1);
    }

    f32x4 sc[2][4] = {{}, {}};
    #pragma unroll
    for (int ks = 0; ks < 2; ++ks) {
      const int hc = (ks << 2) + q;
      #pragma unroll
      for (int ni = 0; ni < 4; ++ni) {
        const int kr = (ni << 4) + ln;
        const bf16x8 ak = *(const bf16x8*)&Ks[((kr << 3) + (hc ^ (kr & 7))) << 3];
        #pragma unroll
        for (int g = 0; g < 2; ++g)
          sc[g][ni] = __builtin_amdgcn_mfma_f32_16x16x32_bf16(ak, qf[g][ks], sc[g][ni], 0, 0, 0);
      }
    }

    unsigned pk01[2][4], pk23[2][4];
    #pragma unroll
    for (int g = 0; g < 2; ++g)
      #pragma unroll
      for (int ni = 0; ni < 4; ++ni) {
        const float e0 = EXP2(sc[g][ni][0]);
        const float e1 = EXP2(sc[g][ni][1]);
        const float e2 = EXP2(sc[g][ni][2]);
        const float e3 = EXP2(sc[g][ni][3]);
        pk01[g][ni] = pack_bf16_2(e0, e1);
        pk23[g][ni] = pack_bf16_2(e2, e3);
      }

    #pragma unroll
    for (int ks = 0; ks < 2; ++ks) {
      union { unsigned u[4]; bf16x8 v; } bfv[2];
      #pragma unroll
      for (int g = 0; g < 2; ++g) {
        bfv[g].u[0] = pk01[g][(ks << 1) + 0];
        bfv[g].u[1] = pk23[g][(ks << 1) + 0];
        bfv[g].u[2] = pk01[g][(ks << 1) + 1];
        bfv[g].u[3] = pk23[g][(ks << 1) + 1];
      }
      #pragma unroll
      for (int g = 0; g < 2; ++g)
        accL[g] = __builtin_amdgcn_mfma_f32_16x16x32_bf16(ones, bfv[g].v, accL[g], 0, 0, 0);
      const int c = (ks << 2) + q;
      #pragma unroll
      for (int nio = 0; nio < 4; ++nio) {
        const int vr = (nio << 4) + ln;
        const bf16x8 av = *(const bf16x8*)&Vs[((vr << 3) + (c ^ (vr & 7))) << 3];
        #pragma unroll
        for (int g = 0; g < 2; ++g)
          accO[g][nio] = __builtin_amdgcn_mfma_f32_16x16x32_bf16(av, bfv[g].v, accO[g][nio], 0, 0, 0);
      }
    }
  }

  if (q == 0) {
    #pragma unroll
    for (int g = 0; g < 2; ++g) {
      const int token = q0 + (w << 5) + (g << 4) + ln;
      ls[(z << 16) + (bh << 11) + token] = accL[g][0];
    }
  }

  __syncthreads();   // last tile's DS reads done before Os overwrite
  #pragma unroll
  for (int g = 0; g < 2; ++g) {
    const int tl = (w << 5) + (g << 4) + ln;
    #pragma unroll
    for (int nio = 0; nio < 4; ++nio) {
      uint2 pk;
      pk.x = pack_bf16_2(accO[g][nio][0], accO[g][nio][1]);
      pk.y = pack_bf16_2(accO[g][nio][2], accO[g][nio][3]);
      *(uint2*)&smem[tl * 72 + (nio << 4) + (q << 2)] = pk;
    }
  }
  __syncthreads();
  u16t* const pbuf = z ? p1 : p0;
  const int h = bh & (NHD - 1), bi = bh >> 4;
  #pragma unroll
  for (int it = 0; it < 4; ++it) {
    const int u = (it << 8) + tid;
    const int tl = u >> 3, c8 = u & 7;
    const uint4 vv = *(const uint4*)&smem[tl * 72 + (c8 << 3)];
    *(uint4*)&pbuf[((size_t)(bi * SEQL + q0 + tl)) * DM + (h << 6) + (c8 << 3)] = vv;
  }
}

// ---------------------------------------------------------------------------
// Key-split reduce: ctx = (O0 + O1) / (l0 + l1), elementwise, in place in p0.
// ---------------------------------------------------------------------------
__global__ __launch_bounds__(256) void reduce_kernel(
    u16t* __restrict__ p0, const u16t* __restrict__ p1,
    const float* __restrict__ ls)
{
  const int gid = blockIdx.x * 256 + threadIdx.x;
  const int i8 = gid << 3;                 // elem index, 8 bf16 per thread
  const int ng = i8 >> 10;                 // b*2048 + n
  const int d  = i8 & 1023;
  const int h  = d >> 6;
  const int b  = ng >> 11;
  const int n  = ng & (SEQL - 1);
  const int li = (((b << 4) + h) << 11) + n;
  const float inv = 1.0f / (ls[li] + ls[65536 + li]);

  const uint4 a = *(const uint4*)(p0 + i8);
  const uint4 c = *(const uint4*)(p1 + i8);
  uint4 o;
  {
    const unsigned ua[4] = { a.x, a.y, a.z, a.w };
    const unsigned uc[4] = { c.x, c.y, c.z, c.w };
    unsigned uo[4];
    #pragma unroll
    for (int i = 0; i < 4; ++i) {
      const float lo = __uint_as_float(ua[i] << 16) + __uint_as_float(uc[i] << 16);
      const float hi = __uint_as_float(ua[i] & 0xFFFF0000u) + __uint_as_float(uc[i] & 0xFFFF0000u);
      uo[i] = pack_bf16_2(lo * inv, hi * inv);
    }
    o.x = uo[0]; o.y = uo[1]; o.z = uo[2]; o.w = uo[3];
  }
  *(uint4*)(p0 + i8) = o;
}

// ---------------------------------------------------------------------------
// Output projection: Y = X @ W^T + bias, fp32 row-major out.
// Tile 128(token) x 64(col): grid (16,32) = 512 blocks = 2 blocks/CU
// (vs 1 block/CU at 128x128) for 2x latency hiding. GLL double-buffered.
// LDS: A dbuf 2x8KB + B dbuf 2x4KB = 24 KB.
// ---------------------------------------------------------------------------
__global__ __launch_bounds__(256) void outproj_kernel(
    const u16t* __restrict__ A, const u16t* __restrict__ W,
    const float* __restrict__ bias, float* __restrict__ outF)
{
  __shared__ alignas(16) u16t smem[12288];  // A0@0 B0@4096 A1@6144 B1@10240

  const int tid = threadIdx.x;
  const int l = tid & 63, w = tid >> 6, q = l >> 4, ln = l & 15;
  const int row0 = blockIdx.y << 7;   // token base
  const int col0 = blockIdx.x << 6;   // col base
  const int wm = (w >> 1) << 6, wn = (w & 1) << 5;

  // A staging: 512 units, 2/thread; B staging: 256 units, 1/thread
  const int s0 = tid, s1 = tid + 256;
  const int m0 = s0 >> 2, kc0 = (s0 & 3) ^ ((m0 >> 1) & 3);
  const int m1 = s1 >> 2, kc1 = (s1 & 3) ^ ((m1 >> 1) & 3);
  const int mB = tid >> 2, kcB = (tid & 3) ^ ((mB >> 1) & 3);
  const u16t* const gA0 = A + (size_t)(row0 + m0) * DM + (kc0 << 3);
  const u16t* const gA1 = A + (size_t)(row0 + m1) * DM + (kc1 << 3);
  const u16t* const gB  = W + (size_t)(col0 + mB) * DM + (kcB << 3);
  const int dA0 = (w << 6) << 3;
  const int dA1 = ((w << 6) + 256) << 3;
  const int dB  = (w << 6) << 3;

  f32x4 acc[4][2] = {};

  GLL16(gA0, smem + dA0);
  GLL16(gA1, smem + dA1);
  GLL16(gB,  smem + 4096 + dB);

  for (int t = 0; t < 32; ++t) {
    u16t* const curA = smem + ((t & 1) ? 6144 : 0);
    u16t* const curB = smem + ((t & 1) ? 10240 : 4096);
    __syncthreads();                 // tile t loads complete; prev reads done
    if (t + 1 < 32) {
      u16t* const nA = smem + ((t & 1) ? 0 : 6144);
      u16t* const nB = smem + ((t & 1) ? 4096 : 10240);
      const int kt = (t + 1) << 5;
      GLL16(gA0 + kt, nA + dA0);
      GLL16(gA1 + kt, nA + dA1);
      GLL16(gB + kt,  nB + dB);
    }

    bf16x8 af[4], bfr[2];
    #pragma unroll
    for (int mi = 0; mi < 4; ++mi)
      af[mi] = *(const bf16x8*)&curA[gslot(wm + (mi << 4) + ln, q) << 3];
    #pragma unroll
    for (int ni = 0; ni < 2; ++ni)
      bfr[ni] = *(const bf16x8*)&curB[gslot(wn + (ni << 4) + ln, q) << 3];
    #pragma unroll
    for (int mi = 0; mi < 4; ++mi)
      #pragma unroll
      for (int ni = 0; ni < 2; ++ni)
        acc[mi][ni] = __builtin_amdgcn_mfma_f32_16x16x32_bf16(af[mi], bfr[ni], acc[mi][ni], 0, 0, 0);
  }

  #pragma unroll
  for (int ni = 0; ni < 2; ++ni) {
    const int col = col0 + wn + (ni << 4) + ln;
    const float bv = bias[col];
    #pragma unroll
    for (int mi = 0; mi < 4; ++mi)
      #pragma unroll
      for (int r = 0; r < 4; ++r) {
        const int row = row0 + wm + (mi << 4) + (q << 2) + r;
        outF[(size_t)row * DM + col] = acc[mi][ni][r] + bv;
      }
  }
}

// ---------------------------------------------------------------------------
extern "C" void kernel_launch(void* const* d_in, const int* in_sizes, int n_in,
                              void* d_out, int out_size, void* d_ws, size_t ws_size,
                              hipStream_t stream)
{
  const float* x  = (const float*)d_in[0];
  const float* Wq = (const float*)d_in[1];
  const float* bq = (const float*)d_in[2];
  const float* Wk = (const float*)d_in[3];
  const float* bk = (const float*)d_in[4];
  const float* Wv = (const float*)d_in[5];
  const float* bv = (const float*)d_in[6];
  const float* Wo = (const float*)d_in[7];
  const float* bo = (const float*)d_in[8];
  float* out = (float*)d_out;

  u16t* p = (u16t*)d_ws;
  u16t* xb  = p;  p += 4194304;   // x bf16; reused as partial O (split 1) after qkv
  u16t* Wqb = p;  p += 1048576;   // reused as lsum (float[2][32][2048]) after qkv
  u16t* Wkb = p;  p += 1048576;
  u16t* Wvb = p;  p += 1048576;
  u16t* Wob = p;  p += 1048576;
  u16t* Qbf = p;  p += 4194304;
  u16t* Kbf = p;  p += 4194304;
  u16t* Vtb = p;  p += 4194304;
  u16t* ctx = p;  p += 4194304;   // partial O (split 0), reduced in place

  ConvArgs ca;
  ca.src[0] = x;  ca.dst[0] = xb;
  ca.src[1] = Wq; ca.dst[1] = Wqb;
  ca.src[2] = Wk; ca.dst[2] = Wkb;
  ca.src[3] = Wv; ca.dst[3] = Wvb;
  ca.src[4] = Wo; ca.dst[4] = Wob;
  conv_kernel<<<8192, 256, 0, stream>>>(ca);

  QKVArgs qa;
  qa.W[0] = Wqb; qa.W[1] = Wkb; qa.W[2] = Wvb;
  qa.b[0] = bq;  qa.b[1] = bk;  qa.b[2] = bv;
  qa.dst[0] = Qbf; qa.dst[1] = Kbf; qa.dst[2] = Vtb;
  qkv_kernel<<<dim3(8, 32, 3), 256, 0, stream>>>(xb, qa);

  float* lsum = (float*)Wqb;   // Wqb dead after qkv
  attn_kernel<<<dim3(16, 32, 2), 256, 0, stream>>>(Qbf, Kbf, Vtb, ctx, xb, lsum);

  reduce_kernel<<<2048, 256, 0, stream>>>(ctx, xb, lsum);

  outproj_kernel<<<dim3(16, 32), 256, 0, stream>>>(ctx, Wob, bo, out);
}